// Round 11
// baseline (814.742 us; speedup 1.0000x reference)
//
#include <hip/hip_runtime.h>

#define TT 4096
#define NB 512
#define NH 10
#define NL 8
#define KS 16          // timesteps per barrier interval
#define NTI (TT/KS)    // 256 t-intervals per layer
#define NI (NTI + NL - 1)

// ---- DPP lane exchange within each row of 16 lanes (VALU pipe, no LDS) ----
//   row_shr:N -> dst lane i gets src lane i-N ; row_shl:N -> lane i+N
__device__ __forceinline__ float dpp_xor1(float v) {   // quad_perm [1,0,3,2]
    return __int_as_float(__builtin_amdgcn_update_dpp(
        __float_as_int(v), __float_as_int(v), 0xB1, 0xF, 0xF, false));
}
__device__ __forceinline__ float dpp_xor2(float v) {   // quad_perm [2,3,0,1]
    return __int_as_float(__builtin_amdgcn_update_dpp(
        __float_as_int(v), __float_as_int(v), 0x4E, 0xF, 0xF, false));
}
__device__ __forceinline__ float dpp_xor4(float v) {
    // banks 0,2 (h&4==0) need lane h+4 -> row_shl:4 ; banks 1,3 need h-4 -> row_shr:4
    int t = __builtin_amdgcn_update_dpp(
        __float_as_int(v), __float_as_int(v), 0x104, 0xF, 0x5, false); // shl:4
    t = __builtin_amdgcn_update_dpp(
        t, __float_as_int(v), 0x114, 0xF, 0xA, false);                 // shr:4
    return __int_as_float(t);
}
// xor8 applied ONLY to rows 2,3 (lanes 32-63); rows 0,1 keep the old value.
__device__ __forceinline__ float dpp_xor8_hi(float v) {
    return __int_as_float(__builtin_amdgcn_update_dpp(
        __float_as_int(v), __float_as_int(v), 0x128, 0xC, 0xF, false)); // row_ror:8
}
// Sum of the two 32-lane halves, delivered to every lane:
// after swap, (a + b) = lo_partial + hi_partial in all 64 lanes.
__device__ __forceinline__ float half_sum(float z) {
    float a = z, bq = z;
    asm volatile("s_nop 1\n\tv_permlane32_swap_b32 %0, %1"
                 : "+v"(a), "+v"(bq));
    return a + bq;
}

// 8 waves/block (wave = layer), 2 batches/wave, each batch replicated across
// the two 32-lane halves; half m owns terms j in {8m..8m+7} of every 16-dot.
// Grid = 256 blocks -> every CU. Cross-layer handoff: producer writes its
// PARTIAL projection (one b32/step) to a pad-17 slab; the consumer's per-step
// permlane32 combine sums the halves. One barrier per KS steps.
__global__ __launch_bounds__(512, 1)
void rnn_pipe(const float* __restrict__ x, const float* __restrict__ h0,
              const float* __restrict__ w_ih0, const float* __restrict__ w_ih_rest,
              const float* __restrict__ w_hh, const float* __restrict__ b_ih,
              const float* __restrict__ b_hh, const float* __restrict__ w_lin,
              const float* __restrict__ b_lin, float* __restrict__ out)
{
    // [parity][producer_layer][lane][16 k's + pad]
    __shared__ float pbuf[2][NL-1][64][17];            // 60928 B

    const int tid  = threadIdx.x;
    const int wv   = tid >> 6;          // layer index
    const int lane = tid & 63;
    const int half = lane >> 5;         // which 8-term slice of the dots
    const int bg   = (lane >> 4) & 1;   // batch within wave
    const int h    = lane & 15;         // hidden unit (padded 10->16)
    const int b    = blockIdx.x * 2 + bg;
    const int off  = half << 3;

    const float SC = 2.8853900817779268f;   // 2*log2(e), folded into z

    // ---- per-lane weights, pre-permuted: X[j] is the coef of r[j]=th[h^j^off]
    float W[8];     // own recurrence whh (SC-folded)
    float WN[8];    // wv<7: consumer's wih (SC-folded); wv==7: w_lin
    float w0s = 0.f, bias2h = 0.f, bias2p = 0.f;
    const float blin = b_lin[0];

    #pragma unroll
    for (int j = 0; j < 8; ++j) {
        const int src = h ^ j ^ off;
        W[j] = (h < NH && src < NH) ? SC * w_hh[(wv*NH + h)*NH + src] : 0.f;
        if (wv < NL-1)   // layer wv+1's W_ih = w_ih_rest[wv]
            WN[j] = (h < NH && src < NH) ? SC * w_ih_rest[(wv*NH + h)*NH + src] : 0.f;
        else
            WN[j] = (src < NH) ? w_lin[src] : 0.f;
    }
    if (h < NH && half == 0) {          // bias/x terms live in half 0 only
        const float bb = SC * (b_ih[wv*NH + h] + b_hh[wv*NH + h]);
        if (wv == 0) { w0s = SC * w_ih0[h]; bias2p = bb; }
        else bias2h = bb;
    }

    // ---- state init: r[j] = h0 of unit h^j^off ----
    const size_t hbase = ((size_t)wv*NB + b)*NH;
    float r[8];
    #pragma unroll
    for (int j = 0; j < 8; ++j) {
        const int src = h ^ j ^ off;
        r[j] = (src < NH) ? h0[hbase + src] : 0.f;
    }

    const int bpbase = (lane & 48) << 2;     // bpermute base (16-lane group)
    float xc = 0.f, xn = 0.f, yst = 0.f;
    if (wv == 0) xn = x[(size_t)b*TT + h];

    for (int i = 0; i < NI; ++i) {
        if ((unsigned)(i - wv) < (unsigned)NTI) {            // wave-uniform
            const int t0 = (i - wv) * KS;
            const int wr = i & 1, rd = wr ^ 1;

            // ---- phase 1: fetch p[0..15] (partial sums; half1 gets 0 for wv0)
            float p[KS];
            if (wv == 0) {
                xc = xn;
                const int tn = t0 + KS;
                xn = (tn < TT) ? x[(size_t)b*TT + tn + h] : 0.f;
                #pragma unroll
                for (int k = 0; k < KS; ++k) {
                    const float xs = __uint_as_float(__builtin_amdgcn_ds_bpermute(
                        bpbase + (k << 2), __float_as_uint(xc)));
                    p[k] = fmaf(w0s, xs, bias2p);            // 0 in half1 / pad lanes
                }
            } else {
                const float* prow = &pbuf[rd][wv-1][lane][0];
                #pragma unroll
                for (int k = 0; k < KS; ++k) p[k] = prow[k]; // 16x ds_read_b32
            }
            float* pw = &pbuf[wr][wv < NL-1 ? wv : 0][lane][0];

            // ---- phase 2: serial recurrence (registers + DPP + 1 permlane) ----
            float th = 0.f;
            #pragma unroll
            for (int k = 0; k < KS; ++k) {
                float z0 = fmaf(W[0], r[0], p[k]);
                float z1 = fmaf(W[1], r[1], bias2h);
                float z2 = W[2] * r[2];
                float z3 = W[3] * r[3];
                z0 = fmaf(W[4], r[4], z0);
                z1 = fmaf(W[5], r[5], z1);
                z2 = fmaf(W[6], r[6], z2);
                z3 = fmaf(W[7], r[7], z3);
                const float zp = (z0 + z1) + (z2 + z3);      // this half's partial
                const float z  = half_sum(zp);               // full 16-term dot
                const float u  = __builtin_amdgcn_exp2f(z);  // z pre-scaled 2*log2e
                th = fmaf(-2.f, __builtin_amdgcn_rcpf(u + 1.f), 1.f);

                // rebuild r[j] = th[h^j^off]: masked xor8 + 8-op cascade
                r[0] = dpp_xor8_hi(th);
                r[4] = dpp_xor4(r[0]);
                r[1] = dpp_xor1(r[0]);  r[5] = dpp_xor1(r[4]);
                r[2] = dpp_xor2(r[0]);  r[3] = dpp_xor2(r[1]);
                r[6] = dpp_xor2(r[4]);  r[7] = dpp_xor2(r[5]);

                // second tree: consumer projection partial / final linear partial
                float n0 = WN[0] * r[0];
                float n1 = WN[1] * r[1];
                float n2 = WN[2] * r[2];
                float n3 = WN[3] * r[3];
                n0 = fmaf(WN[4], r[4], n0);
                n1 = fmaf(WN[5], r[5], n1);
                n2 = fmaf(WN[6], r[6], n2);
                n3 = fmaf(WN[7], r[7], n3);
                const float np = (n0 + n1) + (n2 + n3);

                if (wv < NL-1) {
                    pw[k] = np;                              // partial; no combine
                } else {
                    const float y = half_sum(np) + blin;     // full y(t0+k)
                    if (h == k) yst = y;
                }
            }

            if (wv == NL-1 && lane < 32)                     // half0: 2b x 16t
                out[(size_t)b*TT + t0 + h] = yst;
            if (t0 + KS == TT && lane < 32 && h < NH)        // final hidden state
                out[(size_t)NB*TT + ((size_t)wv*NB + b)*NH + h] = th;
        }
        __syncthreads();
    }
}

extern "C" void kernel_launch(void* const* d_in, const int* in_sizes, int n_in,
                              void* d_out, int out_size, void* d_ws, size_t ws_size,
                              hipStream_t stream) {
    const float* x         = (const float*)d_in[0];
    const float* h0        = (const float*)d_in[1];
    const float* w_ih0     = (const float*)d_in[2];
    const float* w_ih_rest = (const float*)d_in[3];
    const float* w_hh      = (const float*)d_in[4];
    const float* b_ih      = (const float*)d_in[5];
    const float* b_hh      = (const float*)d_in[6];
    const float* w_lin     = (const float*)d_in[7];
    const float* b_lin     = (const float*)d_in[8];
    float* out = (float*)d_out;

    rnn_pipe<<<dim3(NB / 2), dim3(512), 0, stream>>>(
        x, h0, w_ih0, w_ih_rest, w_hh, b_ih, b_hh, w_lin, b_lin, out);
}

// Round 12
// 791.383 us; speedup vs baseline: 1.0295x; 1.0295x over previous
//
#include <hip/hip_runtime.h>

#define TT 4096
#define NB 512
#define NH 10
#define NL 8
#define KS 16          // timesteps per barrier interval
#define NTI (TT/KS)    // 256 t-intervals per layer
#define NI (NTI + NL - 1)

typedef float v2f __attribute__((ext_vector_type(2)));

__device__ __forceinline__ v2f pk_fma(v2f a, v2f b, v2f c) {
    v2f d;
    asm("v_pk_fma_f32 %0, %1, %2, %3" : "=v"(d) : "v"(a), "v"(b), "v"(c));
    return d;
}

// ---- DPP lane exchange within each row of 16 lanes (VALU pipe, no LDS) ----
__device__ __forceinline__ float dpp_xor1(float v) {   // quad_perm [1,0,3,2]
    return __int_as_float(__builtin_amdgcn_update_dpp(
        __float_as_int(v), __float_as_int(v), 0xB1, 0xF, 0xF, false));
}
__device__ __forceinline__ float dpp_xor2(float v) {   // quad_perm [2,3,0,1]
    return __int_as_float(__builtin_amdgcn_update_dpp(
        __float_as_int(v), __float_as_int(v), 0x4E, 0xF, 0xF, false));
}
__device__ __forceinline__ float dpp_xor4(float v) {
    // banks 0,2 (h&4==0) need lane h+4 -> row_shl:4 ; banks 1,3 need h-4 -> row_shr:4
    int t = __builtin_amdgcn_update_dpp(
        __float_as_int(v), __float_as_int(v), 0x104, 0xF, 0x5, false); // shl:4
    t = __builtin_amdgcn_update_dpp(
        t, __float_as_int(v), 0x114, 0xF, 0xA, false);                 // shr:4
    return __int_as_float(t);
}
// xor8 applied ONLY to rows 2,3 (lanes 32-63); rows 0,1 keep the old value.
__device__ __forceinline__ float dpp_xor8_hi(float v) {
    return __int_as_float(__builtin_amdgcn_update_dpp(
        __float_as_int(v), __float_as_int(v), 0x128, 0xC, 0xF, false)); // row_ror:8
}
// Sum of the two 32-lane halves, delivered to every lane.
__device__ __forceinline__ float half_sum(float z) {
    float a = z, bq = z;
    asm volatile("s_nop 1\n\tv_permlane32_swap_b32 %0, %1"
                 : "+v"(a), "+v"(bq));
    return a + bq;
}

// 8 waves/block (wave = layer), 2 batches/wave, each batch replicated across
// the two 32-lane halves; half m owns terms j in {8m..8m+7} of every 16-dot.
// Grid = 256 blocks -> every CU. Producer writes its PARTIAL next-layer
// projection (one b32/step); consumer's per-step permlane32 combine sums the
// halves. Dot trees run as packed-f32 pairs (v_pk_fma_f32) over R[4] pairs
// produced directly by the DPP butterfly. One barrier per KS steps.
__global__ __launch_bounds__(512, 1)
void rnn_pipe(const float* __restrict__ x, const float* __restrict__ h0,
              const float* __restrict__ w_ih0, const float* __restrict__ w_ih_rest,
              const float* __restrict__ w_hh, const float* __restrict__ b_ih,
              const float* __restrict__ b_hh, const float* __restrict__ w_lin,
              const float* __restrict__ b_lin, float* __restrict__ out)
{
    // [parity][producer_layer][lane][16 k's + pad]
    __shared__ float pbuf[2][NL-1][64][17];            // 60928 B

    const int tid  = threadIdx.x;
    const int wv   = tid >> 6;          // layer index
    const int lane = tid & 63;
    const int half = lane >> 5;         // which 8-term slice of the dots
    const int bg   = (lane >> 4) & 1;   // batch within wave
    const int h    = lane & 15;         // hidden unit (padded 10->16)
    const int b    = blockIdx.x * 2 + bg;
    const int off  = half << 3;

    const float SC = 2.8853900817779268f;   // 2*log2(e), folded into z

    // ---- per-lane weights, pre-permuted + paired: X[j] ~ coef of
    //      R[j] = (th[h^(2j)^off], th[h^(2j+1)^off])
    v2f WZ[4];     // own recurrence whh (SC-folded)
    v2f WN[4];     // wv<7: consumer's wih (SC-folded); wv==7: w_lin
    float w0s = 0.f, bias2h = 0.f, bias2p = 0.f;
    const float blin = b_lin[0];

    #pragma unroll
    for (int j = 0; j < 8; ++j) {
        const int src = h ^ j ^ off;
        float wz = (h < NH && src < NH) ? SC * w_hh[(wv*NH + h)*NH + src] : 0.f;
        float wn;
        if (wv < NL-1)   // layer wv+1's W_ih = w_ih_rest[wv]
            wn = (h < NH && src < NH) ? SC * w_ih_rest[(wv*NH + h)*NH + src] : 0.f;
        else
            wn = (src < NH) ? w_lin[src] : 0.f;
        if (j & 1) { WZ[j >> 1].y = wz; WN[j >> 1].y = wn; }
        else       { WZ[j >> 1].x = wz; WN[j >> 1].x = wn; }
    }
    if (h < NH && half == 0) {          // bias/x terms live in half 0 only
        const float bb = SC * (b_ih[wv*NH + h] + b_hh[wv*NH + h]);
        if (wv == 0) { w0s = SC * w_ih0[h]; bias2p = bb; }
        else bias2h = bb;
    }
    const v2f BIAS2 = {0.f, bias2h};    // loop-invariant z-seed pair
    const v2f ZERO2 = {0.f, 0.f};

    // ---- state init: R[j] = (h0[h^2j^off], h0[h^(2j+1)^off]) ----
    const size_t hbase = ((size_t)wv*NB + b)*NH;
    v2f R[4];
    #pragma unroll
    for (int j = 0; j < 8; ++j) {
        const int src = h ^ j ^ off;
        const float v = (src < NH) ? h0[hbase + src] : 0.f;
        if (j & 1) R[j >> 1].y = v; else R[j >> 1].x = v;
    }

    const int bpbase = (lane & 48) << 2;     // bpermute base (16-lane group)
    float xc = 0.f, xn = 0.f, yst = 0.f, th = 0.f;
    if (wv == 0) xn = x[(size_t)b*TT + h];

    for (int i = 0; i < NI; ++i) {
        if ((unsigned)(i - wv) < (unsigned)NTI) {            // wave-uniform
            const int t0 = (i - wv) * KS;
            const int wr = i & 1, rd = wr ^ 1;

            // ---- phase 1: fetch p[0..15] (partial sums; 0 in half1 for wv0)
            float p[KS];
            if (wv == 0) {
                xc = xn;
                const int tn = t0 + KS;
                xn = (tn < TT) ? x[(size_t)b*TT + tn + h] : 0.f;
                #pragma unroll
                for (int k = 0; k < KS; ++k) {
                    const float xs = __uint_as_float(__builtin_amdgcn_ds_bpermute(
                        bpbase + (k << 2), __float_as_uint(xc)));
                    p[k] = fmaf(w0s, xs, bias2p);
                }
            } else {
                const float* prow = &pbuf[rd][wv-1][lane][0];
                #pragma unroll
                for (int k = 0; k < KS; ++k) p[k] = prow[k]; // 16x ds_read_b32
            }
            float* pw = &pbuf[wr][wv < NL-1 ? wv : 0][lane][0];
            float npst[KS];

            // ---- phase 2: serial recurrence (pk trees + DPP + 1 permlane) ----
            #pragma unroll
            for (int k = 0; k < KS; ++k) {
                // z = p + bias + W.r  (4 pk_fma + 2 folds)
                v2f az = pk_fma(WZ[0], R[0], BIAS2);
                az = pk_fma(WZ[1], R[1], az);
                az = pk_fma(WZ[2], R[2], az);
                az = pk_fma(WZ[3], R[3], az);
                const float zp = (az.x + p[k]) + az.y;       // this half's partial
                const float z  = half_sum(zp);               // full 16-term dot
                const float u  = __builtin_amdgcn_exp2f(z);  // z pre-scaled 2*log2e
                th = fmaf(-2.f, __builtin_amdgcn_rcpf(u + 1.f), 1.f);

                // rebuild R[j] pairs: masked xor8 + cascade (9 DPP)
                const float t0r = dpp_xor8_hi(th);           // th[h ^ 8*half]
                R[0].x = t0r;
                R[0].y = dpp_xor1(t0r);
                R[1].x = dpp_xor2(t0r);
                R[1].y = dpp_xor2(R[0].y);
                const float t4r = dpp_xor4(t0r);
                R[2].x = t4r;
                R[2].y = dpp_xor1(t4r);
                R[3].x = dpp_xor2(t4r);
                R[3].y = dpp_xor2(R[2].y);

                // second tree: consumer projection / final-linear partial
                v2f an = pk_fma(WN[0], R[0], ZERO2);
                an = pk_fma(WN[1], R[1], an);
                an = pk_fma(WN[2], R[2], an);
                an = pk_fma(WN[3], R[3], an);
                const float np = an.x + an.y;

                if (wv < NL-1) pw[k] = np;                   // 1x ds_write_b32
                else           npst[k] = np;                 // stage for epilogue
            }

            // ---- phase 3: wave-7 epilogue (off the serial chain) ----
            if (wv == NL-1) {
                #pragma unroll
                for (int k = 0; k < KS; ++k) {
                    const float y = half_sum(npst[k]) + blin;
                    if (h == k) yst = y;
                }
                if (lane < 32)
                    out[(size_t)b*TT + t0 + h] = yst;        // 16 y's per interval
            }
            if (t0 + KS == TT && lane < 32 && h < NH)        // final hidden state
                out[(size_t)NB*TT + ((size_t)wv*NB + b)*NH + h] = th;
        }
        __syncthreads();
    }
}

extern "C" void kernel_launch(void* const* d_in, const int* in_sizes, int n_in,
                              void* d_out, int out_size, void* d_ws, size_t ws_size,
                              hipStream_t stream) {
    const float* x         = (const float*)d_in[0];
    const float* h0        = (const float*)d_in[1];
    const float* w_ih0     = (const float*)d_in[2];
    const float* w_ih_rest = (const float*)d_in[3];
    const float* w_hh      = (const float*)d_in[4];
    const float* b_ih      = (const float*)d_in[5];
    const float* b_hh      = (const float*)d_in[6];
    const float* w_lin     = (const float*)d_in[7];
    const float* b_lin     = (const float*)d_in[8];
    float* out = (float*)d_out;

    rnn_pipe<<<dim3(NB / 2), dim3(512), 0, stream>>>(
        x, h0, w_ih0, w_ih_rest, w_hh, b_ih, b_hh, w_lin, b_lin, out);
}

// Round 13
// 682.569 us; speedup vs baseline: 1.1936x; 1.1594x over previous
//
#include <hip/hip_runtime.h>

#define TT 4096
#define NB 512
#define NH 10
#define NL 8
#define KS 16          // timesteps per barrier interval
#define NTI (TT/KS)    // 256 t-intervals per layer
#define NI (NTI + NL - 1)

typedef float v2f __attribute__((ext_vector_type(2)));

__device__ __forceinline__ v2f pk_fma(v2f a, v2f b, v2f c) {
    v2f d;
    asm("v_pk_fma_f32 %0, %1, %2, %3" : "=v"(d) : "v"(a), "v"(b), "v"(c));
    return d;
}

// ---- DPP lane exchange within each row of 16 lanes (VALU pipe, no LDS) ----
__device__ __forceinline__ float dpp_xor1(float v) {   // quad_perm [1,0,3,2]
    return __int_as_float(__builtin_amdgcn_update_dpp(
        __float_as_int(v), __float_as_int(v), 0xB1, 0xF, 0xF, false));
}
__device__ __forceinline__ float dpp_xor2(float v) {   // quad_perm [2,3,0,1]
    return __int_as_float(__builtin_amdgcn_update_dpp(
        __float_as_int(v), __float_as_int(v), 0x4E, 0xF, 0xF, false));
}
__device__ __forceinline__ float dpp_xor4(float v) {
    // banks 0,2 (h&4==0) need lane h+4 -> row_shl:4 ; banks 1,3 need h-4 -> row_shr:4
    int t = __builtin_amdgcn_update_dpp(
        __float_as_int(v), __float_as_int(v), 0x104, 0xF, 0x5, false); // shl:4
    t = __builtin_amdgcn_update_dpp(
        t, __float_as_int(v), 0x114, 0xF, 0xA, false);                 // shr:4
    return __int_as_float(t);
}
// xor8 applied ONLY to rows 2,3 (lanes 32-63); rows 0,1 keep the old value.
__device__ __forceinline__ float dpp_xor8_hi(float v) {
    return __int_as_float(__builtin_amdgcn_update_dpp(
        __float_as_int(v), __float_as_int(v), 0x128, 0xC, 0xF, false)); // row_ror:8
}
// Sum of the two 32-lane halves, delivered to every lane.
__device__ __forceinline__ float half_sum(float z) {
    float a = z, bq = z;
    asm volatile("s_nop 1\n\tv_permlane32_swap_b32 %0, %1"
                 : "+v"(a), "+v"(bq));
    return a + bq;
}

// 8 waves/block (wave = layer), 2 batches/wave, each batch replicated across
// the two 32-lane halves; half m owns terms j in {8m..8m+7} of every 16-dot.
// Grid = 256 blocks -> every CU. The serial 16-step loop is pure VALU+DPP:
// producer partials are staged in register pairs and written to LDS ONCE per
// interval (8x ds_write_b64); consumer reads them as 8x ds_read_b64.
// One barrier per KS steps.
__global__ __launch_bounds__(512, 1)
void rnn_pipe(const float* __restrict__ x, const float* __restrict__ h0,
              const float* __restrict__ w_ih0, const float* __restrict__ w_ih_rest,
              const float* __restrict__ w_hh, const float* __restrict__ b_ih,
              const float* __restrict__ b_hh, const float* __restrict__ w_lin,
              const float* __restrict__ b_lin, float* __restrict__ out)
{
    // [parity][producer_layer][lane][16 k's + pad2] (72 B rows, 8 B aligned)
    __shared__ float pbuf[2][NL-1][64][18];            // 64512 B

    const int tid  = threadIdx.x;
    const int wv   = tid >> 6;          // layer index
    const int lane = tid & 63;
    const int half = lane >> 5;         // which 8-term slice of the dots
    const int bg   = (lane >> 4) & 1;   // batch within wave
    const int h    = lane & 15;         // hidden unit (padded 10->16)
    const int b    = blockIdx.x * 2 + bg;
    const int off  = half << 3;

    const float SC = 2.8853900817779268f;   // 2*log2(e), folded into z

    // ---- per-lane weights, pre-permuted + paired: X[j] ~ coef of
    //      R[j] = (th[h^(2j)^off], th[h^(2j+1)^off])
    v2f WZ[4];     // own recurrence whh (SC-folded)
    v2f WN[4];     // wv<7: consumer's wih (SC-folded); wv==7: w_lin
    float w0s = 0.f, bias2h = 0.f, bias2p = 0.f;
    const float blin = b_lin[0];

    #pragma unroll
    for (int j = 0; j < 8; ++j) {
        const int src = h ^ j ^ off;
        float wz = (h < NH && src < NH) ? SC * w_hh[(wv*NH + h)*NH + src] : 0.f;
        float wn;
        if (wv < NL-1)   // layer wv+1's W_ih = w_ih_rest[wv]
            wn = (h < NH && src < NH) ? SC * w_ih_rest[(wv*NH + h)*NH + src] : 0.f;
        else
            wn = (src < NH) ? w_lin[src] : 0.f;
        if (j & 1) { WZ[j >> 1].y = wz; WN[j >> 1].y = wn; }
        else       { WZ[j >> 1].x = wz; WN[j >> 1].x = wn; }
    }
    if (h < NH && half == 0) {          // bias/x terms live in half 0 only
        const float bb = SC * (b_ih[wv*NH + h] + b_hh[wv*NH + h]);
        if (wv == 0) { w0s = SC * w_ih0[h]; bias2p = bb; }
        else bias2h = bb;
    }
    const v2f BIAS2 = {0.f, bias2h};    // loop-invariant z-seed pair
    const v2f ZERO2 = {0.f, 0.f};
    const v2f W0S2  = {w0s, w0s};
    const v2f BIASP2= {bias2p, bias2p};

    // ---- state init: R[j] = (h0[h^2j^off], h0[h^(2j+1)^off]) ----
    const size_t hbase = ((size_t)wv*NB + b)*NH;
    v2f R[4];
    #pragma unroll
    for (int j = 0; j < 8; ++j) {
        const int src = h ^ j ^ off;
        const float v = (src < NH) ? h0[hbase + src] : 0.f;
        if (j & 1) R[j >> 1].y = v; else R[j >> 1].x = v;
    }

    const int bpbase = (lane & 48) << 2;     // bpermute base (16-lane group)
    float xc = 0.f, xn = 0.f, yst = 0.f, th = 0.f;
    if (wv == 0) xn = x[(size_t)b*TT + h];

    for (int i = 0; i < NI; ++i) {
        if ((unsigned)(i - wv) < (unsigned)NTI) {            // wave-uniform
            const int t0 = (i - wv) * KS;
            const int wr = i & 1, rd = wr ^ 1;

            // ---- phase 1: fetch p pairs (partial sums; 0 in half1 for wv0)
            v2f pp[8];
            if (wv == 0) {
                xc = xn;
                const int tn = t0 + KS;
                xn = (tn < TT) ? x[(size_t)b*TT + tn + h] : 0.f;
                #pragma unroll
                for (int j = 0; j < 8; ++j) {
                    const float xs0 = __uint_as_float(__builtin_amdgcn_ds_bpermute(
                        bpbase + ((2*j) << 2), __float_as_uint(xc)));
                    const float xs1 = __uint_as_float(__builtin_amdgcn_ds_bpermute(
                        bpbase + ((2*j+1) << 2), __float_as_uint(xc)));
                    pp[j] = pk_fma(W0S2, (v2f){xs0, xs1}, BIASP2);
                }
            } else {
                const v2f* prow = (const v2f*)&pbuf[rd][wv-1][lane][0];
                #pragma unroll
                for (int j = 0; j < 8; ++j) pp[j] = prow[j];  // 8x ds_read_b64
            }
            v2f nps[8];

            // ---- phase 2: serial recurrence — pure VALU+DPP, no LDS ----
            #pragma unroll
            for (int k = 0; k < KS; ++k) {
                // z = p + bias + W.r  (4 pk_fma + 2 folds)
                v2f az = pk_fma(WZ[0], R[0], BIAS2);
                az = pk_fma(WZ[1], R[1], az);
                az = pk_fma(WZ[2], R[2], az);
                az = pk_fma(WZ[3], R[3], az);
                const float pk_ = (k & 1) ? pp[k >> 1].y : pp[k >> 1].x;
                const float zp = (az.x + pk_) + az.y;        // this half's partial
                const float z  = half_sum(zp);               // full 16-term dot
                const float u  = __builtin_amdgcn_exp2f(z);  // z pre-scaled 2*log2e
                th = fmaf(-2.f, __builtin_amdgcn_rcpf(u + 1.f), 1.f);

                // rebuild R[j] pairs: masked xor8 + cascade (9 DPP)
                const float t0r = dpp_xor8_hi(th);           // th[h ^ 8*half]
                R[0].x = t0r;
                R[0].y = dpp_xor1(t0r);
                R[1].x = dpp_xor2(t0r);
                R[1].y = dpp_xor2(R[0].y);
                const float t4r = dpp_xor4(t0r);
                R[2].x = t4r;
                R[2].y = dpp_xor1(t4r);
                R[3].x = dpp_xor2(t4r);
                R[3].y = dpp_xor2(R[2].y);

                // second tree: consumer projection / final-linear partial
                v2f an = pk_fma(WN[0], R[0], ZERO2);
                an = pk_fma(WN[1], R[1], an);
                an = pk_fma(WN[2], R[2], an);
                an = pk_fma(WN[3], R[3], an);
                const float np = an.x + an.y;
                if (k & 1) nps[k >> 1].y = np;               // stage in regs
                else       nps[k >> 1].x = np;
            }

            // ---- phase 3: interval-boundary traffic (off the serial chain) ----
            if (wv < NL-1) {
                v2f* pwr = (v2f*)&pbuf[wr][wv][lane][0];
                #pragma unroll
                for (int j = 0; j < 8; ++j) pwr[j] = nps[j]; // 8x ds_write_b64
            } else {
                #pragma unroll
                for (int k = 0; k < KS; ++k) {
                    const float np = (k & 1) ? nps[k >> 1].y : nps[k >> 1].x;
                    const float y = half_sum(np) + blin;
                    if (h == k) yst = y;
                }
                if (lane < 32)
                    out[(size_t)b*TT + t0 + h] = yst;        // 16 y's per interval
            }
            if (t0 + KS == TT && lane < 32 && h < NH)        // final hidden state
                out[(size_t)NB*TT + ((size_t)wv*NB + b)*NH + h] = th;
        }
        __syncthreads();
    }
}

extern "C" void kernel_launch(void* const* d_in, const int* in_sizes, int n_in,
                              void* d_out, int out_size, void* d_ws, size_t ws_size,
                              hipStream_t stream) {
    const float* x         = (const float*)d_in[0];
    const float* h0        = (const float*)d_in[1];
    const float* w_ih0     = (const float*)d_in[2];
    const float* w_ih_rest = (const float*)d_in[3];
    const float* w_hh      = (const float*)d_in[4];
    const float* b_ih      = (const float*)d_in[5];
    const float* b_hh      = (const float*)d_in[6];
    const float* w_lin     = (const float*)d_in[7];
    const float* b_lin     = (const float*)d_in[8];
    float* out = (float*)d_out;

    rnn_pipe<<<dim3(NB / 2), dim3(512), 0, stream>>>(
        x, h0, w_ih0, w_ih_rest, w_hh, b_ih, b_hh, w_lin, b_lin, out);
}

// Round 14
// 650.499 us; speedup vs baseline: 1.2525x; 1.0493x over previous
//
#include <hip/hip_runtime.h>

#define TT 4096
#define NB 512
#define NH 10
#define NL 8
#define KS 32                  // timesteps per barrier interval
#define PADK 34                // row stride (floats): even -> 8B-aligned b64
#define NTI (TT/KS)            // 128 t-intervals per layer
#define NI (NTI + NL - 1)      // 135
#define LDSBYTES (2*(NL-1)*64*PADK*4)   // 121856 B dynamic LDS

typedef float v2f __attribute__((ext_vector_type(2)));

// ---- packed f32 FMA with op_sel broadcast of one src1 half ----
// acc(z,n) += (WZ_m, WN_m) * r_m ; r_m broadcast from lo/hi half of the R pair.
__device__ __forceinline__ v2f pk_fma_blo(v2f a, v2f b, v2f c) {
    v2f d;
    asm("v_pk_fma_f32 %0, %1, %2, %3 op_sel:[0,0,0] op_sel_hi:[1,0,1]"
        : "=v"(d) : "v"(a), "v"(b), "v"(c));
    return d;
}
__device__ __forceinline__ v2f pk_fma_bhi(v2f a, v2f b, v2f c) {
    v2f d;
    asm("v_pk_fma_f32 %0, %1, %2, %3 op_sel:[0,1,0] op_sel_hi:[1,1,1]"
        : "=v"(d) : "v"(a), "v"(b), "v"(c));
    return d;
}
__device__ __forceinline__ v2f pk_fma(v2f a, v2f b, v2f c) {   // plain packed
    v2f d;
    asm("v_pk_fma_f32 %0, %1, %2, %3" : "=v"(d) : "v"(a), "v"(b), "v"(c));
    return d;
}

// ---- DPP lane exchange within each row of 16 lanes (VALU pipe, no LDS) ----
__device__ __forceinline__ float dpp_xor1(float v) {   // quad_perm [1,0,3,2]
    return __int_as_float(__builtin_amdgcn_update_dpp(
        __float_as_int(v), __float_as_int(v), 0xB1, 0xF, 0xF, false));
}
__device__ __forceinline__ float dpp_xor2(float v) {   // quad_perm [2,3,0,1]
    return __int_as_float(__builtin_amdgcn_update_dpp(
        __float_as_int(v), __float_as_int(v), 0x4E, 0xF, 0xF, false));
}
__device__ __forceinline__ float dpp_xor4(float v) {
    int t = __builtin_amdgcn_update_dpp(
        __float_as_int(v), __float_as_int(v), 0x104, 0xF, 0x5, false); // shl:4
    t = __builtin_amdgcn_update_dpp(
        t, __float_as_int(v), 0x114, 0xF, 0xA, false);                 // shr:4
    return __int_as_float(t);
}
// xor8 applied ONLY to rows 2,3 (lanes 32-63); rows 0,1 keep the old value.
__device__ __forceinline__ float dpp_xor8_hi(float v) {
    return __int_as_float(__builtin_amdgcn_update_dpp(
        __float_as_int(v), __float_as_int(v), 0x128, 0xC, 0xF, false)); // row_ror:8
}
// Sum of the two 32-lane halves, delivered to every lane.
__device__ __forceinline__ float half_sum(float z) {
    float a = z, bq = z;
    asm volatile("s_nop 1\n\tv_permlane32_swap_b32 %0, %1"
                 : "+v"(a), "+v"(bq));
    return a + bq;
}

// 8 waves/block (wave = layer), 2 batches/wave replicated across the two
// 32-lane halves; half m owns terms j in {8m..8m+7} of every 16-dot.
// Grid = 256 blocks -> every CU. Per step, ONE dual-packed tree (8 pk_fma,
// op_sel) yields z(k) and np(k-1) together from the same state r(k-1).
// Producer partials staged in regs, written once per interval (16 b64).
// One barrier per KS=32 steps (dynamic LDS 119 KB).
__global__ __launch_bounds__(512, 1)
void rnn_pipe(const float* __restrict__ x, const float* __restrict__ h0,
              const float* __restrict__ w_ih0, const float* __restrict__ w_ih_rest,
              const float* __restrict__ w_hh, const float* __restrict__ b_ih,
              const float* __restrict__ b_hh, const float* __restrict__ w_lin,
              const float* __restrict__ b_lin, float* __restrict__ out)
{
    extern __shared__ float pbuf[];     // [2][NL-1][64][PADK]

    const int tid  = threadIdx.x;
    const int wv   = tid >> 6;          // layer index
    const int lane = tid & 63;
    const int half = lane >> 5;         // which 8-term slice of the dots
    const int bg   = (lane >> 4) & 1;   // batch within wave
    const int h    = lane & 15;         // hidden unit (padded 10->16)
    const int b    = blockIdx.x * 2 + bg;
    const int off  = half << 3;
    const int slot = (half << 4) | h;   // 0..31 (t-slot within interval)

    const float SC = 2.8853900817779268f;   // 2*log2(e), folded into z

    // ---- per-lane weights, pre-permuted + dual-packed:
    //      WP[m] = (SC*whh[h][h^m^off],  SC*wih_next[h][h^m^off] or w_lin)
    v2f WP[8];
    float w0s = 0.f, bias2h = 0.f, bias2p = 0.f;
    const float blin = b_lin[0];

    #pragma unroll
    for (int m = 0; m < 8; ++m) {
        const int src = h ^ m ^ off;
        float wz = (h < NH && src < NH) ? SC * w_hh[(wv*NH + h)*NH + src] : 0.f;
        float wn;
        if (wv < NL-1)
            wn = (h < NH && src < NH) ? SC * w_ih_rest[(wv*NH + h)*NH + src] : 0.f;
        else
            wn = (src < NH) ? w_lin[src] : 0.f;
        WP[m] = (v2f){wz, wn};
    }
    if (h < NH && half == 0) {          // bias/x terms live in half 0 only
        const float bb = SC * (b_ih[wv*NH + h] + b_hh[wv*NH + h]);
        if (wv == 0) { w0s = SC * w_ih0[h]; bias2p = bb; }
        else bias2h = bb;
    }
    const v2f DSEED = {bias2h, 0.f};    // (z-seed, n-seed)
    const v2f W0S2  = {w0s, w0s};
    const v2f BIASP2= {bias2p, bias2p};

    // ---- state init: R[j] = (h0[h^2j^off], h0[h^(2j+1)^off]) ----
    const size_t hbase = ((size_t)wv*NB + b)*NH;
    v2f R[4];
    #pragma unroll
    for (int j = 0; j < 8; ++j) {
        const int src = h ^ j ^ off;
        const float v = (src < NH) ? h0[hbase + src] : 0.f;
        if (j & 1) R[j >> 1].y = v; else R[j >> 1].x = v;
    }

    // LDS row pointers (consumer reads producer wv-1; producer writes slab wv)
    float* prow_rd = pbuf + (((size_t)0)              );   // set per interval (parity)
    const int rdbase = (wv > 0) ? (wv-1)*64 + lane : lane; // layer-1 slab row
    const int wrbase = (wv < NL-1 ? wv : 0)*64 + lane;
    const int PARITY = (NL-1)*64*PADK;                     // floats per parity

    float xc = 0.f, xn = 0.f, yst = 0.f, th = 0.f;
    if (wv == 0) xn = x[(size_t)b*TT + slot];

    for (int i = 0; i < NI; ++i) {
        if ((unsigned)(i - wv) < (unsigned)NTI) {            // wave-uniform
            const int t0 = (i - wv) * KS;
            const int wr = i & 1, rd = wr ^ 1;

            // ---- phase 1: fetch p pairs (partials; 0 in half1 for wv0) ----
            v2f pp[KS/2];
            if (wv == 0) {
                xc = xn;
                const int tn = t0 + KS;
                xn = (tn < TT) ? x[(size_t)b*TT + tn + slot] : 0.f;
                const int bgs = bg << 4;
                #pragma unroll
                for (int j = 0; j < KS/2; ++j) {
                    const int k0 = 2*j, k1 = 2*j + 1;
                    const int a0 = ((((k0 >> 4) << 5) | bgs | (k0 & 15)) << 2);
                    const int a1 = ((((k1 >> 4) << 5) | bgs | (k1 & 15)) << 2);
                    const float xs0 = __uint_as_float(
                        __builtin_amdgcn_ds_bpermute(a0, __float_as_uint(xc)));
                    const float xs1 = __uint_as_float(
                        __builtin_amdgcn_ds_bpermute(a1, __float_as_uint(xc)));
                    pp[j] = pk_fma(W0S2, (v2f){xs0, xs1}, BIASP2);
                }
            } else {
                const v2f* prow = (const v2f*)(pbuf + rd*PARITY + rdbase*PADK);
                #pragma unroll
                for (int j = 0; j < KS/2; ++j) pp[j] = prow[j]; // ds_read_b64
            }
            v2f nps[KS/2];

            // ---- phase 2: serial recurrence — dual tree + DPP, no LDS ----
            #pragma unroll
            for (int k = 0; k < KS; ++k) {
                // acc = (z_k partial-sans-p, np_{k-1} partial), both from r(k-1)
                v2f acc = pk_fma_blo(WP[0], R[0], DSEED);
                acc = pk_fma_bhi(WP[1], R[0], acc);
                acc = pk_fma_blo(WP[2], R[1], acc);
                acc = pk_fma_bhi(WP[3], R[1], acc);
                acc = pk_fma_blo(WP[4], R[2], acc);
                acc = pk_fma_bhi(WP[5], R[2], acc);
                acc = pk_fma_blo(WP[6], R[3], acc);
                acc = pk_fma_bhi(WP[7], R[3], acc);

                if (k > 0) {                                  // np for step k-1
                    if ((k-1) & 1) nps[(k-1) >> 1].y = acc.y;
                    else           nps[(k-1) >> 1].x = acc.y;
                }
                const float pk_ = (k & 1) ? pp[k >> 1].y : pp[k >> 1].x;
                const float zp  = acc.x + pk_;               // half partial
                const float z   = half_sum(zp);              // full 16-term dot
                const float u   = __builtin_amdgcn_exp2f(z); // pre-scaled 2*log2e
                th = fmaf(-2.f, __builtin_amdgcn_rcpf(u + 1.f), 1.f);

                // rebuild R[j] pairs: masked xor8 + cascade (9 DPP)
                const float t0r = dpp_xor8_hi(th);           // th[h ^ 8*half]
                R[0].x = t0r;
                R[0].y = dpp_xor1(t0r);
                R[1].x = dpp_xor2(t0r);
                R[1].y = dpp_xor2(R[0].y);
                const float t4r = dpp_xor4(t0r);
                R[2].x = t4r;
                R[2].y = dpp_xor1(t4r);
                R[3].x = dpp_xor2(t4r);
                R[3].y = dpp_xor2(R[2].y);
            }
            {   // post-loop extra tree: np_{KS-1} from final state
                v2f acc = pk_fma_blo(WP[0], R[0], DSEED);
                acc = pk_fma_bhi(WP[1], R[0], acc);
                acc = pk_fma_blo(WP[2], R[1], acc);
                acc = pk_fma_bhi(WP[3], R[1], acc);
                acc = pk_fma_blo(WP[4], R[2], acc);
                acc = pk_fma_bhi(WP[5], R[2], acc);
                acc = pk_fma_blo(WP[6], R[3], acc);
                acc = pk_fma_bhi(WP[7], R[3], acc);
                nps[(KS-1) >> 1].y = acc.y;                  // KS-1 odd -> .y
            }

            // ---- phase 3: interval-boundary traffic ----
            if (wv < NL-1) {
                v2f* pwr = (v2f*)(pbuf + wr*PARITY + wrbase*PADK);
                #pragma unroll
                for (int j = 0; j < KS/2; ++j) pwr[j] = nps[j]; // ds_write_b64
            } else {
                #pragma unroll
                for (int j = 0; j < KS; ++j) {
                    const float nv = (j & 1) ? nps[j >> 1].y : nps[j >> 1].x;
                    const float y  = half_sum(nv) + blin;
                    if (slot == j) yst = y;
                }
                out[(size_t)b*TT + t0 + slot] = yst;         // 2b x 32t coalesced
            }
            if (t0 + KS == TT && lane < 32 && h < NH)        // final hidden state
                out[(size_t)NB*TT + ((size_t)wv*NB + b)*NH + h] = th;
        }
        __syncthreads();
    }
}

extern "C" void kernel_launch(void* const* d_in, const int* in_sizes, int n_in,
                              void* d_out, int out_size, void* d_ws, size_t ws_size,
                              hipStream_t stream) {
    const float* x         = (const float*)d_in[0];
    const float* h0        = (const float*)d_in[1];
    const float* w_ih0     = (const float*)d_in[2];
    const float* w_ih_rest = (const float*)d_in[3];
    const float* w_hh      = (const float*)d_in[4];
    const float* b_ih      = (const float*)d_in[5];
    const float* b_hh      = (const float*)d_in[6];
    const float* w_lin     = (const float*)d_in[7];
    const float* b_lin     = (const float*)d_in[8];
    float* out = (float*)d_out;

    // gfx950 has 160 KiB LDS/CU; opt in above the 64 KiB default (capture-safe,
    // host-side, idempotent).
    hipFuncSetAttribute(reinterpret_cast<const void*>(&rnn_pipe),
                        hipFuncAttributeMaxDynamicSharedMemorySize, LDSBYTES);

    rnn_pipe<<<dim3(NB / 2), dim3(512), LDSBYTES, stream>>>(
        x, h0, w_ih0, w_ih_rest, w_hh, b_ih, b_hh, w_lin, b_lin, out);
}